// Round 9
// baseline (288.248 us; speedup 1.0000x reference)
//
#include <hip/hip_runtime.h>

#define N_PTS 131072
#define TD 4096
#define DD 64
#define KK 1024
#define MARGIN_TH 2e-3f

typedef short bf16x8 __attribute__((ext_vector_type(8)));
typedef float f32x4  __attribute__((ext_vector_type(4)));

__device__ inline unsigned short f2bf(float f) {           // RNE float->bf16
    unsigned u = __float_as_uint(f);
    unsigned r = u + 0x7FFFu + ((u >> 16) & 1u);
    return (unsigned short)(r >> 16);
}
__device__ inline float bf2f(unsigned short h) {
    return __uint_as_float(((unsigned)h) << 16);
}

__device__ inline void gload_lds16(const unsigned short* g, unsigned short* l) {
    __builtin_amdgcn_global_load_lds(
        (const __attribute__((address_space(1))) unsigned int*)g,
        (__attribute__((address_space(3))) unsigned int*)l, 16, 0, 0);
}

// ---------------- K0: fused prep ----------------
// blocks 0..2047: transpose z[B,D,T] -> NEGATED z_hi/z_lo bf16 [N,D]
// blocks 2048..2051: emb -> MFMA-fragment-ordered e_hi/e_lo + half norms
//   (f32 for the screen, fp64 dnn for the fallback rescan)
__global__ __launch_bounds__(256) void vq_prep(const float* __restrict__ z,
                                               unsigned short* __restrict__ zh,
                                               unsigned short* __restrict__ zl,
                                               const float* __restrict__ emb,
                                               unsigned short* __restrict__ efh,
                                               unsigned short* __restrict__ efl,
                                               float* __restrict__ halfnorm,
                                               double* __restrict__ dnn)
{
    __shared__ float tile[64][65];
    const int tid = threadIdx.x;

    if (blockIdx.x >= 2048) {                    // ---- eprep role (4 blocks) ----
        const int k = (blockIdx.x - 2048) * 256 + tid;   // 0..1023
        const int t = k >> 4, col = k & 15;
        const float* e = emb + (size_t)k * DD;
        double s = 0.0;
#pragma unroll
        for (int d = 0; d < DD; ++d) {
            const float v = e[d];
            const double dv = (double)v;
            s = fma(dv, dv, s);
            const unsigned short h = f2bf(v);
            const int q = d >> 3, j = d & 7;
            const size_t pos = (size_t)t * 1024 + (q >> 2) * 512 + ((q & 3) * 16 + col) * 8 + j;
            efh[pos] = h;
            efl[pos] = f2bf(v - bf2f(h));
        }
        halfnorm[k] = (float)(0.5 * s);
        dnn[k] = 0.5 * s;
        return;
    }

    // ---- transpose role ----
    const int b = blockIdx.x >> 6;
    const int t0 = (blockIdx.x & 63) * 64;

    const int d = tid >> 2, tq = tid & 3;
#pragma unroll
    for (int it = 0; it < 4; ++it) {
        const int tt = tq * 16 + it * 4;
        const float4 v = *(const float4*)(z + ((size_t)b * DD + d) * TD + t0 + tt);
        tile[d][tt] = v.x; tile[d][tt + 1] = v.y; tile[d][tt + 2] = v.z; tile[d][tt + 3] = v.w;
    }
    __syncthreads();

    const int p = tid >> 2, dg = tid & 3;
    bf16x8 h0, h1, l0, l1;
#pragma unroll
    for (int j = 0; j < 8; ++j) {
        const float v0 = -tile[dg * 16 + j][p];
        const unsigned short a = f2bf(v0);
        h0[j] = (short)a; l0[j] = (short)f2bf(v0 - bf2f(a));
        const float v1 = -tile[dg * 16 + 8 + j][p];
        const unsigned short c = f2bf(v1);
        h1[j] = (short)c; l1[j] = (short)f2bf(v1 - bf2f(c));
    }
    const size_t o = ((size_t)(b * TD + t0 + p)) * DD + dg * 16;
    *(bf16x8*)(zh + o) = h0;
    *(bf16x8*)(zh + o + 8) = h1;
    *(bf16x8*)(zl + o) = l0;
    *(bf16x8*)(zl + o + 8) = l1;
}

// ---------------- K1: MFMA screen v9 — 32 pts/wave, counted-vmcnt DMA ring ----------
// r8 accounting: ds_read_b128 was the widest pipe (~41 us aggregate). v9 halves it:
// each wave owns TWO point-tiles (A = 32 VGPR); the same 4 ds_read_b128 per code-tile
// feed 12 MFMAs in two independent 6-chains. Grid 1024 x 256 thr -> 4 blocks/CU,
// 16 waves/CU (vs r8's 24) but 2x per-wave MFMA ILP. Staging ring + counted vmcnt
// unchanged from r8 (proven). hn in persistent LDS; no other vm ops in the loop.
__global__ __launch_bounds__(256, 4) void vq_screen_mfma(
    const unsigned short* __restrict__ zh, const unsigned short* __restrict__ zl,
    const unsigned short* __restrict__ efh, const unsigned short* __restrict__ efl,
    const float* __restrict__ hn,
    int* __restrict__ idx_ws, float* __restrict__ ind_out,
    int* __restrict__ nflag, int* __restrict__ flags)
{
    __shared__ __align__(16) unsigned short tiles[4][2048];  // 16 KB ring (4 KB/tile: eh|el)
    __shared__ float hns[KK];                                // 4 KB persistent halfnorms

    const int tid  = threadIdx.x;
    const int lane = tid & 63;
    const int wv   = tid >> 6;          // 0..3
    const int quad = lane >> 4;
    const int col  = lane & 15;
    const int loff = lane * 8;
    const int pbase = blockIdx.x * 128 + wv * 32;   // 32 points per wave

    // A fragments: two point-tiles (zh/zl hold -z)
    const bf16x8* ph0 = (const bf16x8*)(zh + (size_t)(pbase + col) * DD + quad * 8);
    const bf16x8* pl0 = (const bf16x8*)(zl + (size_t)(pbase + col) * DD + quad * 8);
    const bf16x8* ph1 = (const bf16x8*)(zh + (size_t)(pbase + 16 + col) * DD + quad * 8);
    const bf16x8* pl1 = (const bf16x8*)(zl + (size_t)(pbase + 16 + col) * DD + quad * 8);
    const bf16x8 A0h0 = ph0[0], A0h1 = ph0[4];
    const bf16x8 A0l0 = pl0[0], A0l1 = pl0[4];
    const bf16x8 A1h0 = ph1[0], A1h1 = ph1[4];
    const bf16x8 A1l0 = pl1[0], A1l1 = pl1[4];

    // persistent halfnorms -> LDS (one float4 per thread)
    ((float4*)hns)[tid] = ((const float4*)hn)[tid];

    // staging source: thread tid owns 16B chunk tid of each 4 KB tile (eh 2KB | el 2KB)
    const unsigned short* sg = (tid < 128) ? (efh + tid * 8) : (efl + (tid - 128) * 8);

    // pin: all prologue vm ops complete BEFORE any tile DMA -> in-loop vmcnt counts DMAs only
    asm volatile("s_waitcnt vmcnt(0)" ::: "memory");
    __builtin_amdgcn_sched_barrier(0);
    __syncthreads();

#define STAGE(T) gload_lds16(sg + (size_t)(T) * 1024, &tiles[(T) & 3][tid * 8])

    STAGE(0);
    STAGE(1);

    float best0[4]  = {1e30f, 1e30f, 1e30f, 1e30f};
    float best20[4] = {1e30f, 1e30f, 1e30f, 1e30f};
    int   bidx0[4]  = {0, 0, 0, 0};
    float best1[4]  = {1e30f, 1e30f, 1e30f, 1e30f};
    float best21[4] = {1e30f, 1e30f, 1e30f, 1e30f};
    int   bidx1[4]  = {0, 0, 0, 0};

#define BODY(T)                                                                     \
    {                                                                               \
        const unsigned short* buf = &tiles[(T) & 3][0];                             \
        const bf16x8 Bh0 = *(const bf16x8*)(buf + loff);                            \
        const bf16x8 Bh1 = *(const bf16x8*)(buf + 512 + loff);                      \
        const bf16x8 Bl0 = *(const bf16x8*)(buf + 1024 + loff);                     \
        const bf16x8 Bl1 = *(const bf16x8*)(buf + 1536 + loff);                     \
        const float chn = hns[(T) * 16 + col];                                      \
        f32x4 a0 = {chn, chn, chn, chn};                                            \
        f32x4 a1 = {chn, chn, chn, chn};                                            \
        a0 = __builtin_amdgcn_mfma_f32_16x16x32_bf16(A0h0, Bh0, a0, 0, 0, 0);       \
        a1 = __builtin_amdgcn_mfma_f32_16x16x32_bf16(A1h0, Bh0, a1, 0, 0, 0);       \
        a0 = __builtin_amdgcn_mfma_f32_16x16x32_bf16(A0h1, Bh1, a0, 0, 0, 0);       \
        a1 = __builtin_amdgcn_mfma_f32_16x16x32_bf16(A1h1, Bh1, a1, 0, 0, 0);       \
        a0 = __builtin_amdgcn_mfma_f32_16x16x32_bf16(A0l0, Bh0, a0, 0, 0, 0);       \
        a1 = __builtin_amdgcn_mfma_f32_16x16x32_bf16(A1l0, Bh0, a1, 0, 0, 0);       \
        a0 = __builtin_amdgcn_mfma_f32_16x16x32_bf16(A0l1, Bh1, a0, 0, 0, 0);       \
        a1 = __builtin_amdgcn_mfma_f32_16x16x32_bf16(A1l1, Bh1, a1, 0, 0, 0);       \
        a0 = __builtin_amdgcn_mfma_f32_16x16x32_bf16(A0h0, Bl0, a0, 0, 0, 0);       \
        a1 = __builtin_amdgcn_mfma_f32_16x16x32_bf16(A1h0, Bl0, a1, 0, 0, 0);       \
        a0 = __builtin_amdgcn_mfma_f32_16x16x32_bf16(A0h1, Bl1, a0, 0, 0, 0);       \
        a1 = __builtin_amdgcn_mfma_f32_16x16x32_bf16(A1h1, Bl1, a1, 0, 0, 0);       \
        const int code = (T) * 16 + col;                                            \
        _Pragma("unroll")                                                           \
        for (int r = 0; r < 4; ++r) {                                               \
            const float s0 = a0[r];                                                 \
            best20[r] = __builtin_amdgcn_fmed3f(best0[r], best20[r], s0);           \
            bidx0[r] = (s0 < best0[r]) ? code : bidx0[r];                           \
            best0[r] = fminf(best0[r], s0);                                         \
            const float s1 = a1[r];                                                 \
            best21[r] = __builtin_amdgcn_fmed3f(best1[r], best21[r], s1);           \
            bidx1[r] = (s1 < best1[r]) ? code : bidx1[r];                           \
            best1[r] = fminf(best1[r], s1);                                         \
        }                                                                           \
    }

    for (int t = 0; t < 62; ++t) {
        STAGE(t + 2);                                      // depth-2 prefetch, stays in flight
        asm volatile("s_waitcnt vmcnt(2)" ::: "memory");   // tile t landed; t+1,t+2 in flight
        __builtin_amdgcn_sched_barrier(0);
        __builtin_amdgcn_s_barrier();                      // raw barrier: no vmcnt(0) drain
        __builtin_amdgcn_sched_barrier(0);
        BODY(t);
    }
    // peeled tail: counts shrink as issues stop
    asm volatile("s_waitcnt vmcnt(1)" ::: "memory");
    __builtin_amdgcn_sched_barrier(0);
    __builtin_amdgcn_s_barrier();
    __builtin_amdgcn_sched_barrier(0);
    BODY(62);
    asm volatile("s_waitcnt vmcnt(0)" ::: "memory");
    __builtin_amdgcn_sched_barrier(0);
    __builtin_amdgcn_s_barrier();
    __builtin_amdgcn_sched_barrier(0);
    BODY(63);

#undef STAGE
#undef BODY

    // merge across the 16 cols of each quad-group (disjoint code sets)
#pragma unroll
    for (int off = 1; off < 16; off <<= 1) {
#pragma unroll
        for (int r = 0; r < 4; ++r) {
            {
                const float ob  = __shfl_xor(best0[r],  off, 64);
                const float ob2 = __shfl_xor(best20[r], off, 64);
                const int   oi  = __shfl_xor(bidx0[r],  off, 64);
                const float nb2 = fminf(fminf(best20[r], ob2), fmaxf(best0[r], ob));
                if (ob < best0[r]) { best0[r] = ob; bidx0[r] = oi; }
                best20[r] = nb2;
            }
            {
                const float ob  = __shfl_xor(best1[r],  off, 64);
                const float ob2 = __shfl_xor(best21[r], off, 64);
                const int   oi  = __shfl_xor(bidx1[r],  off, 64);
                const float nb2 = fminf(fminf(best21[r], ob2), fmaxf(best1[r], ob));
                if (ob < best1[r]) { best1[r] = ob; bidx1[r] = oi; }
                best21[r] = nb2;
            }
        }
    }

    if (col == 0) {
#pragma unroll
        for (int r = 0; r < 4; ++r) {
            const int n0 = pbase + quad * 4 + r;
            idx_ws[n0] = bidx0[r];
            ind_out[n0] = (float)bidx0[r];
            if (best20[r] - best0[r] < MARGIN_TH) {
                const int pos = atomicAdd(nflag, 1);
                flags[pos] = n0;
            }
            const int n1 = pbase + 16 + quad * 4 + r;
            idx_ws[n1] = bidx1[r];
            ind_out[n1] = (float)bidx1[r];
            if (best21[r] - best1[r] < MARGIN_TH) {
                const int pos = atomicAdd(nflag, 1);
                flags[pos] = n1;
            }
        }
    }
}

// ---------------- K1c: fp64 exact rescan for near-tie points (wave per point) ----------
// v9: grid 1024 (was 128 — half the GPU sat idle); codebook fp64 half-norms hoisted
// into dnn[k] (computed once in prep), halving the per-(point,k) fp64 work.
__global__ __launch_bounds__(256) void vq_fallback(
    const float* __restrict__ z, const float* __restrict__ emb,
    const double* __restrict__ dnn,
    int* __restrict__ idx_ws, float* __restrict__ ind_out,
    const int* __restrict__ nflag, const int* __restrict__ flags)
{
    __shared__ float zs[4][DD];
    const int total = *nflag;
    const int lane = threadIdx.x & 63;
    const int wid = threadIdx.x >> 6;
    const int gw = blockIdx.x * 4 + wid;

    for (int i = gw; i < total; i += gridDim.x * 4) {
        const int n = flags[i];
        const int b = n >> 12, t = n & 4095;
        zs[wid][lane] = z[((size_t)b * DD + lane) * TD + t];
        __builtin_amdgcn_s_waitcnt(0);
        double best = 1e300;
        int bi = KK;
        for (int kc = 0; kc < KK / 64; ++kc) {
            const int k = kc * 64 + lane;
            const float4* e = (const float4*)(emb + (size_t)k * DD);
            double dot = 0.0;
#pragma unroll
            for (int j = 0; j < 16; ++j) {
                float4 ev = e[j];
                dot = fma((double)zs[wid][4 * j + 0], (double)ev.x,
                      fma((double)zs[wid][4 * j + 1], (double)ev.y,
                      fma((double)zs[wid][4 * j + 2], (double)ev.z,
                      fma((double)zs[wid][4 * j + 3], (double)ev.w, dot))));
            }
            double s = dnn[k] - dot;
            if (s < best || (s == best && k < bi)) { best = s; bi = k; }
        }
        for (int off = 32; off > 0; off >>= 1) {
            double os = __shfl_down(best, off, 64);
            int oi = __shfl_down(bi, off, 64);
            if (os < best || (os == best && oi < bi)) { best = os; bi = oi; }
        }
        if (lane == 0) { idx_ws[n] = bi; ind_out[n] = (float)bi; }
    }
}

// ---------------- K2a: histogram of final indices (LDS-privatized) ----------------
__global__ __launch_bounds__(256) void vq_hist(const int* __restrict__ idx_ws, int* __restrict__ hist)
{
    __shared__ int h[KK];
    for (int i = threadIdx.x; i < KK; i += 256) h[i] = 0;
    __syncthreads();
    const int base = blockIdx.x * 2048;
#pragma unroll
    for (int j = 0; j < 8; ++j)
        atomicAdd(&h[idx_ws[base + j * 256 + threadIdx.x]], 1);
    __syncthreads();
    for (int i = threadIdx.x; i < KK; i += 256)
        if (h[i]) atomicAdd(&hist[i], h[i]);
}

// ---------------- K2b: exclusive scan -> cursor, plus Laplace smoothing -> rsmo ----------------
__global__ __launch_bounds__(1024) void vq_prefix_smo(
    const int* __restrict__ hist, const float* __restrict__ cs,
    int* __restrict__ cursor, float* __restrict__ rsmo)
{
    __shared__ int tmp[KK];
    __shared__ double dred[KK];
    const int k = threadIdx.x;
    const int c = hist[k];
    tmp[k] = c;
    const double ncs = 0.99 * (double)cs[k] + 0.01 * (double)c;
    dred[k] = ncs;
    __syncthreads();
    for (int off = 1; off < KK; off <<= 1) {
        int u = (k >= off) ? tmp[k - off] : 0;
        __syncthreads();
        tmp[k] += u;
        __syncthreads();
    }
    cursor[k] = tmp[k] - c;  // exclusive
    for (int s = 512; s > 0; s >>= 1) {
        if (k < s) dred[k] += dred[k + s];
        __syncthreads();
    }
    const double nsum = dred[0];
    const double smo = (ncs + 1e-5) / (nsum + (double)KK * 1e-5) * nsum;
    rsmo[k] = (float)(1.0 / smo);
}

// ---------------- K2c: scatter point ids into per-code lists ----------------
__global__ __launch_bounds__(256) void vq_scatter(const int* __restrict__ idx_ws,
                                                  int* __restrict__ cursor, int* __restrict__ order)
{
    const int n = blockIdx.x * 256 + threadIdx.x;
    const int bi = idx_ws[n];
    const int pos = atomicAdd(&cursor[bi], 1);
    order[pos] = n;
}

// ---------------- K2d: balanced segment sum (zh/zl hold -z -> negate at flush) ----------------
__global__ __launch_bounds__(256) void vq_esum2(
    const unsigned short* __restrict__ zh, const unsigned short* __restrict__ zl,
    const int* __restrict__ idx_ws, const int* __restrict__ order,
    float* __restrict__ esum)
{
    const int tid = threadIdx.x;
    const int lane = tid & 63;
    const int w = tid >> 6;
    const int base = blockIdx.x * 256 + w * 64;   // this wave's 64 sorted positions

    const int pid_l = order[base + lane];          // coalesced
    const int code_l = idx_ws[pid_l];              // gather (one per lane)

    float v[64];
#pragma unroll
    for (int j = 0; j < 64; ++j) {
        const int pj = __shfl(pid_l, j, 64);
        const size_t o = (size_t)pj * DD + lane;   // 128 B coalesced per row
        v[j] = bf2f(zh[o]) + bf2f(zl[o]);
    }

    float racc = 0.f;
    int cur = __shfl(code_l, 0, 64);
#pragma unroll
    for (int j = 0; j < 64; ++j) {
        const int cj = __shfl(code_l, j, 64);      // wave-uniform
        if (cj != cur) {
            atomicAdd(&esum[(size_t)cur * DD + lane], -racc);
            racc = 0.f;
            cur = cj;
        }
        racc += v[j];
    }
    atomicAdd(&esum[(size_t)cur * DD + lane], -racc);
}

// ---------------- K3: new embedding (parallel) ----------------
__global__ __launch_bounds__(256) void vq_newE(
    const float* __restrict__ avg, const float* __restrict__ esum,
    const float* __restrict__ rsmo, float* __restrict__ newE)
{
    const int j = blockIdx.x * 256 + threadIdx.x;   // 65536 total
    newE[j] = (float)((0.99 * (double)avg[j] + 0.01 * (double)esum[j]) * (double)rsmo[j >> 6]);
}

// ---------------- K4: gather z_q + commitment loss (finalize fused) ----------------
__global__ __launch_bounds__(256) void vq_gather_loss(
    const float* __restrict__ z, const float* __restrict__ newE,
    const int* __restrict__ idx_ws, float* __restrict__ zq_out,
    double* __restrict__ loss_acc, int* __restrict__ done_cnt,
    float* __restrict__ loss_out)
{
    const int tid = threadIdx.x;
    const int n = blockIdx.x * 256 + tid;
    const int b = n >> 12;
    const int t = n & 4095;
    const float* zb = z + ((size_t)b * DD) * TD + t;
    float* ob = zq_out + ((size_t)b * DD) * TD + t;
    const int bi = idx_ws[n];
    const float* e = newE + (size_t)bi * DD;
    double acc = 0.0;
#pragma unroll
    for (int d = 0; d < DD; ++d) {
        float q = e[d];
        float zv = zb[(size_t)d * TD];
        ob[(size_t)d * TD] = q;
        float df = zv - q;
        acc = fma((double)df, (double)df, acc);
    }
    for (int off = 32; off > 0; off >>= 1) acc += __shfl_down(acc, off, 64);
    __shared__ double wsum[4];
    const int wid = tid >> 6, lane = tid & 63;
    if (lane == 0) wsum[wid] = acc;
    __syncthreads();
    if (tid == 0) {
        atomicAdd(loss_acc, wsum[0] + wsum[1] + wsum[2] + wsum[3]);
        __threadfence();
        const int prev = atomicAdd(done_cnt, 1);
        if (prev == gridDim.x - 1) {
            __threadfence();
            *loss_out = (float)(0.25 * (*loss_acc) / (double)(N_PTS * DD));
        }
    }
}

extern "C" void kernel_launch(void* const* d_in, const int* in_sizes, int n_in,
                              void* d_out, int out_size, void* d_ws, size_t ws_size,
                              hipStream_t stream) {
    const float* z    = (const float*)d_in[0];   // [32, 64, 4096]
    const float* emb  = (const float*)d_in[1];   // [1024, 64]
    const float* cs   = (const float*)d_in[2];   // [1024]
    const float* avg  = (const float*)d_in[3];   // [1024, 64]

    float* out      = (float*)d_out;
    float* zq_out   = out;                // 8388608 floats (32 MiB)
    float* loss_out = out + 8388608;      // 1
    float* ind_out  = out + 8388609;      // 131072 (indices as float)

    // z_hi/z_lo bf16 [N][D] exactly fill the z_q region (dead before K4 rewrites it)
    unsigned short* zh = (unsigned short*)d_out;                       // 16 MiB
    unsigned short* zl = (unsigned short*)((char*)d_out + 16777216);   // 16 MiB

    char* ws = (char*)d_ws;
    int*            idx_ws   = (int*)ws;                     // 512 KB @ 0
    float*          newE     = (float*)(ws + 524288);        // 256 KB
    double*         dnn      = (double*)(ws + 524288);       // 8 KB: lives in newE region
                                                             // (dead until vq_newE, which
                                                             // runs after vq_fallback)
    float*          esum     = (float*)(ws + 786432);        // 256 KB [memset]
    int*            hist     = (int*)(ws + 1048576);         // 4 KB   [memset]
    int*            nflag    = (int*)(ws + 1052672);         // 4 B    [memset]
    int*            done_cnt = (int*)(ws + 1052676);         // 4 B    [memset]
    double*         loss_acc = (double*)(ws + 1052680);      // 8 B    [memset]
    float*          halfnorm = (float*)(ws + 1052688);       // 4 KB
    int*            cursor   = (int*)(ws + 1056784);         // 4 KB
    int*            flags    = (int*)(ws + 1060880);         // 512 KB
    int*            order    = (int*)(ws + 1585168);         // 512 KB
    unsigned short* efh      = (unsigned short*)(ws + 2109456); // 128 KB (fragment-ordered hi)
    unsigned short* efl      = (unsigned short*)(ws + 2240528); // 128 KB (fragment-ordered lo)
    float*          rsmo     = (float*)(ws + 2371600);       // 4 KB (end ~2.38 MB)

    // zero esum + hist + nflag + done_cnt + loss_acc (contiguous 786432..1052688)
    hipMemsetAsync(ws + 786432, 0, 266256, stream);

    vq_prep<<<2052, 256, 0, stream>>>(z, zh, zl, emb, efh, efl, halfnorm, dnn);
    vq_screen_mfma<<<N_PTS / 128, 256, 0, stream>>>(zh, zl, efh, efl, halfnorm,
                                                    idx_ws, ind_out, nflag, flags);
    vq_fallback<<<1024, 256, 0, stream>>>(z, emb, dnn, idx_ws, ind_out, nflag, flags);
    vq_hist<<<64, 256, 0, stream>>>(idx_ws, hist);
    vq_prefix_smo<<<1, 1024, 0, stream>>>(hist, cs, cursor, rsmo);
    vq_scatter<<<N_PTS / 256, 256, 0, stream>>>(idx_ws, cursor, order);
    vq_esum2<<<N_PTS / 256, 256, 0, stream>>>(zh, zl, idx_ws, order, esum);
    vq_newE<<<256, 256, 0, stream>>>(avg, esum, rsmo, newE);
    vq_gather_loss<<<N_PTS / 256, 256, 0, stream>>>(z, newE, idx_ws, zq_out,
                                                    loss_acc, done_cnt, loss_out);
}

// Round 10
// 278.748 us; speedup vs baseline: 1.0341x; 1.0341x over previous
//
#include <hip/hip_runtime.h>

#define N_PTS 131072
#define TD 4096
#define DD 64
#define KK 1024
#define MARGIN_TH 2e-3f

typedef short bf16x8 __attribute__((ext_vector_type(8)));
typedef float f32x4  __attribute__((ext_vector_type(4)));

__device__ inline unsigned short f2bf(float f) {           // RNE float->bf16
    unsigned u = __float_as_uint(f);
    unsigned r = u + 0x7FFFu + ((u >> 16) & 1u);
    return (unsigned short)(r >> 16);
}
__device__ inline float bf2f(unsigned short h) {
    return __uint_as_float(((unsigned)h) << 16);
}

__device__ inline void gload_lds16(const unsigned short* g, unsigned short* l) {
    __builtin_amdgcn_global_load_lds(
        (const __attribute__((address_space(1))) unsigned int*)g,
        (__attribute__((address_space(3))) unsigned int*)l, 16, 0, 0);
}

// ---------------- K0: emb -> MFMA-fragment-ordered e_hi/e_lo + half norms ----------------
// TIGHT layout, 1024 ushorts per 16-code tile (exactly 128 KB per array):
//   code k = t*16+col, dim d = q*8+j (q=0..7, half=q>>2):
//   ef[t*1024 + half*512 + ((q&3)*16 + col)*8 + j]
// halfnorm f32 for the screen; dnn fp64 for the fallback rescan.
__global__ __launch_bounds__(256) void vq_eprep(const float* __restrict__ emb,
                                                unsigned short* __restrict__ efh,
                                                unsigned short* __restrict__ efl,
                                                float* __restrict__ halfnorm,
                                                double* __restrict__ dnn)
{
    const int k = blockIdx.x * 256 + threadIdx.x;
    if (k >= KK) return;
    const int t = k >> 4, col = k & 15;
    const float* e = emb + (size_t)k * DD;
    double s = 0.0;
#pragma unroll
    for (int d = 0; d < DD; ++d) {
        const float v = e[d];
        const double dv = (double)v;
        s = fma(dv, dv, s);
        const unsigned short h = f2bf(v);
        const int q = d >> 3, j = d & 7;
        const size_t pos = (size_t)t * 1024 + (q >> 2) * 512 + ((q & 3) * 16 + col) * 8 + j;
        efh[pos] = h;
        efl[pos] = f2bf(v - bf2f(h));
    }
    halfnorm[k] = (float)(0.5 * s);
    dnn[k] = 0.5 * s;
}

// ---------------- K1: MFMA screen v10 — fused z-transpose + 32 pts/wave + DMA ring --------
// Phase 1: block's 128 points = one contiguous (b, t0..t0+127) slab of z. Load float z
// into LDS [64][129], transpose-extract the wave's A-fragments IN-REGISTER (negated bf16
// hi/lo — no zh/zl round-trip), and store zh/zl rows for esum2 (dense 2 KB/instr).
// Phase 2 (LDS reused): r8/r9's counted-vmcnt DMA ring, 32 pts/wave, 12 MFMA/tile.
// Epilogue: LDS-privatized histogram fused in (ring LDS is dead), fallback repairs.
// LDS = max(33 KB transpose, 20 KB ring+hns) = 33 KB -> 4 blocks/CU.
__global__ __launch_bounds__(256, 4) void vq_screen_mfma(
    const float* __restrict__ z,
    unsigned short* __restrict__ zh, unsigned short* __restrict__ zl,
    const unsigned short* __restrict__ efh, const unsigned short* __restrict__ efl,
    const float* __restrict__ hn,
    int* __restrict__ idx_ws, float* __restrict__ ind_out,
    int* __restrict__ nflag, int* __restrict__ flags, int* __restrict__ hist)
{
    __shared__ __align__(16) char smem[64 * 129 * 4];        // 33024 B phase-union
    float (*tbuf)[129] = (float (*)[129])smem;               // phase 1: z transpose
    unsigned short (*tiles)[2048] = (unsigned short (*)[2048])smem;  // phase 2: 16 KB ring
    float* hns = (float*)(smem + 16384);                     // phase 2: 4 KB halfnorms

    const int tid  = threadIdx.x;
    const int lane = tid & 63;
    const int wv   = tid >> 6;          // 0..3
    const int quad = lane >> 4;
    const int col  = lane & 15;
    const int loff = lane * 8;
    const int pbase = blockIdx.x * 128;          // 128 points per block, contiguous in t
    const int b  = pbase >> 12;                  // batch
    const int t0 = pbase & 4095;                 // t-offset

    // ---- phase 1: load z slab [64 d][128 t] into LDS ----
    {
        const int d = tid >> 2, tq = tid & 3;
#pragma unroll
        for (int it = 0; it < 8; ++it) {
            const int tt = tq * 32 + it * 4;
            const float4 v = *(const float4*)(z + ((size_t)b * DD + d) * TD + t0 + tt);
            tbuf[d][tt] = v.x; tbuf[d][tt + 1] = v.y;
            tbuf[d][tt + 2] = v.z; tbuf[d][tt + 3] = v.w;
        }
    }
    __syncthreads();

    // ---- extract A-fragments (negated bf16 hi/lo) + store zh/zl rows ----
    const int l0 = wv * 32 + col, l1 = l0 + 16;  // local point indices of this lane's cols
    bf16x8 A0h0, A0h1, A0l0, A0l1, A1h0, A1h1, A1l0, A1l1;
#pragma unroll
    for (int j = 0; j < 8; ++j) {
        { const float v = -tbuf[quad * 8 + j][l0];      const unsigned short h = f2bf(v);
          A0h0[j] = (short)h; A0l0[j] = (short)f2bf(v - bf2f(h)); }
        { const float v = -tbuf[32 + quad * 8 + j][l0]; const unsigned short h = f2bf(v);
          A0h1[j] = (short)h; A0l1[j] = (short)f2bf(v - bf2f(h)); }
        { const float v = -tbuf[quad * 8 + j][l1];      const unsigned short h = f2bf(v);
          A1h0[j] = (short)h; A1l0[j] = (short)f2bf(v - bf2f(h)); }
        { const float v = -tbuf[32 + quad * 8 + j][l1]; const unsigned short h = f2bf(v);
          A1h1[j] = (short)h; A1l1[j] = (short)f2bf(v - bf2f(h)); }
    }
    {
        const size_t r0 = (size_t)(pbase + l0) * DD;
        const size_t r1 = (size_t)(pbase + l1) * DD;
        *(bf16x8*)(zh + r0 + quad * 8) = A0h0; *(bf16x8*)(zh + r0 + 32 + quad * 8) = A0h1;
        *(bf16x8*)(zl + r0 + quad * 8) = A0l0; *(bf16x8*)(zl + r0 + 32 + quad * 8) = A0l1;
        *(bf16x8*)(zh + r1 + quad * 8) = A1h0; *(bf16x8*)(zh + r1 + 32 + quad * 8) = A1h1;
        *(bf16x8*)(zl + r1 + quad * 8) = A1l0; *(bf16x8*)(zl + r1 + 32 + quad * 8) = A1l1;
    }
    __syncthreads();                                 // tbuf dead -> reuse as ring+hns

    // persistent halfnorms -> LDS (one float4 per thread)
    ((float4*)hns)[tid] = ((const float4*)hn)[tid];

    // staging source: thread tid owns 16B chunk tid of each 4 KB tile (eh 2KB | el 2KB)
    const unsigned short* sg = (tid < 128) ? (efh + tid * 8) : (efl + (tid - 128) * 8);

    // pin: all prologue vm ops (z loads, zh/zl stores, hns load) complete BEFORE any
    // tile DMA -> in-loop vmcnt counts DMAs only
    asm volatile("s_waitcnt vmcnt(0)" ::: "memory");
    __builtin_amdgcn_sched_barrier(0);
    __syncthreads();

#define STAGE(T) gload_lds16(sg + (size_t)(T) * 1024, &tiles[(T) & 3][tid * 8])

    STAGE(0);
    STAGE(1);

    float best0[4]  = {1e30f, 1e30f, 1e30f, 1e30f};
    float best20[4] = {1e30f, 1e30f, 1e30f, 1e30f};
    int   bidx0[4]  = {0, 0, 0, 0};
    float best1[4]  = {1e30f, 1e30f, 1e30f, 1e30f};
    float best21[4] = {1e30f, 1e30f, 1e30f, 1e30f};
    int   bidx1[4]  = {0, 0, 0, 0};

#define BODY(T)                                                                     \
    {                                                                               \
        const unsigned short* buf = &tiles[(T) & 3][0];                             \
        const bf16x8 Bh0 = *(const bf16x8*)(buf + loff);                            \
        const bf16x8 Bh1 = *(const bf16x8*)(buf + 512 + loff);                      \
        const bf16x8 Bl0 = *(const bf16x8*)(buf + 1024 + loff);                     \
        const bf16x8 Bl1 = *(const bf16x8*)(buf + 1536 + loff);                     \
        const float chn = hns[(T) * 16 + col];                                      \
        f32x4 a0 = {chn, chn, chn, chn};                                            \
        f32x4 a1 = {chn, chn, chn, chn};                                            \
        a0 = __builtin_amdgcn_mfma_f32_16x16x32_bf16(A0h0, Bh0, a0, 0, 0, 0);       \
        a1 = __builtin_amdgcn_mfma_f32_16x16x32_bf16(A1h0, Bh0, a1, 0, 0, 0);       \
        a0 = __builtin_amdgcn_mfma_f32_16x16x32_bf16(A0h1, Bh1, a0, 0, 0, 0);       \
        a1 = __builtin_amdgcn_mfma_f32_16x16x32_bf16(A1h1, Bh1, a1, 0, 0, 0);       \
        a0 = __builtin_amdgcn_mfma_f32_16x16x32_bf16(A0l0, Bh0, a0, 0, 0, 0);       \
        a1 = __builtin_amdgcn_mfma_f32_16x16x32_bf16(A1l0, Bh0, a1, 0, 0, 0);       \
        a0 = __builtin_amdgcn_mfma_f32_16x16x32_bf16(A0l1, Bh1, a0, 0, 0, 0);       \
        a1 = __builtin_amdgcn_mfma_f32_16x16x32_bf16(A1l1, Bh1, a1, 0, 0, 0);       \
        a0 = __builtin_amdgcn_mfma_f32_16x16x32_bf16(A0h0, Bl0, a0, 0, 0, 0);       \
        a1 = __builtin_amdgcn_mfma_f32_16x16x32_bf16(A1h0, Bl0, a1, 0, 0, 0);       \
        a0 = __builtin_amdgcn_mfma_f32_16x16x32_bf16(A0h1, Bl1, a0, 0, 0, 0);       \
        a1 = __builtin_amdgcn_mfma_f32_16x16x32_bf16(A1h1, Bl1, a1, 0, 0, 0);       \
        const int code = (T) * 16 + col;                                            \
        _Pragma("unroll")                                                           \
        for (int r = 0; r < 4; ++r) {                                               \
            const float s0 = a0[r];                                                 \
            best20[r] = __builtin_amdgcn_fmed3f(best0[r], best20[r], s0);           \
            bidx0[r] = (s0 < best0[r]) ? code : bidx0[r];                           \
            best0[r] = fminf(best0[r], s0);                                         \
            const float s1 = a1[r];                                                 \
            best21[r] = __builtin_amdgcn_fmed3f(best1[r], best21[r], s1);           \
            bidx1[r] = (s1 < best1[r]) ? code : bidx1[r];                           \
            best1[r] = fminf(best1[r], s1);                                         \
        }                                                                           \
    }

    for (int t = 0; t < 62; ++t) {
        STAGE(t + 2);                                      // depth-2 prefetch, stays in flight
        asm volatile("s_waitcnt vmcnt(2)" ::: "memory");   // tile t landed; t+1,t+2 in flight
        __builtin_amdgcn_sched_barrier(0);
        __builtin_amdgcn_s_barrier();                      // raw barrier: no vmcnt(0) drain
        __builtin_amdgcn_sched_barrier(0);
        BODY(t);
    }
    // peeled tail: counts shrink as issues stop
    asm volatile("s_waitcnt vmcnt(1)" ::: "memory");
    __builtin_amdgcn_sched_barrier(0);
    __builtin_amdgcn_s_barrier();
    __builtin_amdgcn_sched_barrier(0);
    BODY(62);
    asm volatile("s_waitcnt vmcnt(0)" ::: "memory");
    __builtin_amdgcn_sched_barrier(0);
    __builtin_amdgcn_s_barrier();
    __builtin_amdgcn_sched_barrier(0);
    BODY(63);

#undef STAGE
#undef BODY

    // merge across the 16 cols of each quad-group (disjoint code sets)
#pragma unroll
    for (int off = 1; off < 16; off <<= 1) {
#pragma unroll
        for (int r = 0; r < 4; ++r) {
            {
                const float ob  = __shfl_xor(best0[r],  off, 64);
                const float ob2 = __shfl_xor(best20[r], off, 64);
                const int   oi  = __shfl_xor(bidx0[r],  off, 64);
                const float nb2 = fminf(fminf(best20[r], ob2), fmaxf(best0[r], ob));
                if (ob < best0[r]) { best0[r] = ob; bidx0[r] = oi; }
                best20[r] = nb2;
            }
            {
                const float ob  = __shfl_xor(best1[r],  off, 64);
                const float ob2 = __shfl_xor(best21[r], off, 64);
                const int   oi  = __shfl_xor(bidx1[r],  off, 64);
                const float nb2 = fminf(fminf(best21[r], ob2), fmaxf(best1[r], ob));
                if (ob < best1[r]) { best1[r] = ob; bidx1[r] = oi; }
                best21[r] = nb2;
            }
        }
    }

    // epilogue with fused LDS-privatized histogram (ring LDS is dead)
    __syncthreads();
    int* h = (int*)smem;
    for (int i = tid; i < KK; i += 256) h[i] = 0;
    __syncthreads();

    if (col == 0) {
#pragma unroll
        for (int r = 0; r < 4; ++r) {
            const int n0 = pbase + wv * 32 + quad * 4 + r;
            idx_ws[n0] = bidx0[r];
            ind_out[n0] = (float)bidx0[r];
            atomicAdd(&h[bidx0[r]], 1);
            if (best20[r] - best0[r] < MARGIN_TH) {
                const int pos = atomicAdd(nflag, 1);
                flags[pos] = n0;
            }
            const int n1 = pbase + wv * 32 + 16 + quad * 4 + r;
            idx_ws[n1] = bidx1[r];
            ind_out[n1] = (float)bidx1[r];
            atomicAdd(&h[bidx1[r]], 1);
            if (best21[r] - best1[r] < MARGIN_TH) {
                const int pos = atomicAdd(nflag, 1);
                flags[pos] = n1;
            }
        }
    }
    __syncthreads();
    for (int i = tid; i < KK; i += 256)
        if (h[i]) atomicAdd(&hist[i], h[i]);
}

// ---------------- K1c: fp64 exact rescan for near-tie points + histogram repair ----------
__global__ __launch_bounds__(256) void vq_fallback(
    const float* __restrict__ z, const float* __restrict__ emb,
    const double* __restrict__ dnn,
    int* __restrict__ idx_ws, float* __restrict__ ind_out,
    const int* __restrict__ nflag, const int* __restrict__ flags,
    int* __restrict__ hist)
{
    __shared__ float zs[4][DD];
    const int total = *nflag;
    const int lane = threadIdx.x & 63;
    const int wid = threadIdx.x >> 6;
    const int gw = blockIdx.x * 4 + wid;

    for (int i = gw; i < total; i += gridDim.x * 4) {
        const int n = flags[i];
        const int b = n >> 12, t = n & 4095;
        zs[wid][lane] = z[((size_t)b * DD + lane) * TD + t];
        __builtin_amdgcn_s_waitcnt(0);
        double best = 1e300;
        int bi = KK;
        for (int kc = 0; kc < KK / 64; ++kc) {
            const int k = kc * 64 + lane;
            const float4* e = (const float4*)(emb + (size_t)k * DD);
            double dot = 0.0;
#pragma unroll
            for (int j = 0; j < 16; ++j) {
                float4 ev = e[j];
                dot = fma((double)zs[wid][4 * j + 0], (double)ev.x,
                      fma((double)zs[wid][4 * j + 1], (double)ev.y,
                      fma((double)zs[wid][4 * j + 2], (double)ev.z,
                      fma((double)zs[wid][4 * j + 3], (double)ev.w, dot))));
            }
            double s = dnn[k] - dot;
            if (s < best || (s == best && k < bi)) { best = s; bi = k; }
        }
        for (int off = 32; off > 0; off >>= 1) {
            double os = __shfl_down(best, off, 64);
            int oi = __shfl_down(bi, off, 64);
            if (os < best || (os == best && oi < bi)) { best = os; bi = oi; }
        }
        if (lane == 0) {
            const int old = idx_ws[n];
            if (bi != old) {
                idx_ws[n] = bi;
                ind_out[n] = (float)bi;
                atomicAdd(&hist[old], -1);
                atomicAdd(&hist[bi], 1);
            }
        }
    }
}

// ---------------- K2b: exclusive scan -> cursor, plus Laplace smoothing -> rsmo ----------------
__global__ __launch_bounds__(1024) void vq_prefix_smo(
    const int* __restrict__ hist, const float* __restrict__ cs,
    int* __restrict__ cursor, float* __restrict__ rsmo)
{
    __shared__ int tmp[KK];
    __shared__ double dred[KK];
    const int k = threadIdx.x;
    const int c = hist[k];
    tmp[k] = c;
    const double ncs = 0.99 * (double)cs[k] + 0.01 * (double)c;
    dred[k] = ncs;
    __syncthreads();
    for (int off = 1; off < KK; off <<= 1) {
        int u = (k >= off) ? tmp[k - off] : 0;
        __syncthreads();
        tmp[k] += u;
        __syncthreads();
    }
    cursor[k] = tmp[k] - c;  // exclusive
    for (int s = 512; s > 0; s >>= 1) {
        if (k < s) dred[k] += dred[k + s];
        __syncthreads();
    }
    const double nsum = dred[0];
    const double smo = (ncs + 1e-5) / (nsum + (double)KK * 1e-5) * nsum;
    rsmo[k] = (float)(1.0 / smo);
}

// ---------------- K2c: scatter point ids into per-code lists ----------------
__global__ __launch_bounds__(256) void vq_scatter(const int* __restrict__ idx_ws,
                                                  int* __restrict__ cursor, int* __restrict__ order)
{
    const int n = blockIdx.x * 256 + threadIdx.x;
    const int bi = idx_ws[n];
    const int pos = atomicAdd(&cursor[bi], 1);
    order[pos] = n;
}

// ---------------- K2d: balanced segment sum (zh/zl hold -z -> negate at flush) ----------------
__global__ __launch_bounds__(256) void vq_esum2(
    const unsigned short* __restrict__ zh, const unsigned short* __restrict__ zl,
    const int* __restrict__ idx_ws, const int* __restrict__ order,
    float* __restrict__ esum)
{
    const int tid = threadIdx.x;
    const int lane = tid & 63;
    const int w = tid >> 6;
    const int base = blockIdx.x * 256 + w * 64;   // this wave's 64 sorted positions

    const int pid_l = order[base + lane];          // coalesced
    const int code_l = idx_ws[pid_l];              // gather (one per lane)

    float v[64];
#pragma unroll
    for (int j = 0; j < 64; ++j) {
        const int pj = __shfl(pid_l, j, 64);
        const size_t o = (size_t)pj * DD + lane;   // 128 B coalesced per row
        v[j] = bf2f(zh[o]) + bf2f(zl[o]);
    }

    float racc = 0.f;
    int cur = __shfl(code_l, 0, 64);
#pragma unroll
    for (int j = 0; j < 64; ++j) {
        const int cj = __shfl(code_l, j, 64);      // wave-uniform
        if (cj != cur) {
            atomicAdd(&esum[(size_t)cur * DD + lane], -racc);
            racc = 0.f;
            cur = cj;
        }
        racc += v[j];
    }
    atomicAdd(&esum[(size_t)cur * DD + lane], -racc);
}

// ---------------- K3: new embedding (parallel) ----------------
__global__ __launch_bounds__(256) void vq_newE(
    const float* __restrict__ avg, const float* __restrict__ esum,
    const float* __restrict__ rsmo, float* __restrict__ newE)
{
    const int j = blockIdx.x * 256 + threadIdx.x;   // 65536 total
    newE[j] = (float)((0.99 * (double)avg[j] + 0.01 * (double)esum[j]) * (double)rsmo[j >> 6]);
}

// ---------------- K4: gather z_q + commitment loss (finalize fused) ----------------
__global__ __launch_bounds__(256) void vq_gather_loss(
    const float* __restrict__ z, const float* __restrict__ newE,
    const int* __restrict__ idx_ws, float* __restrict__ zq_out,
    double* __restrict__ loss_acc, int* __restrict__ done_cnt,
    float* __restrict__ loss_out)
{
    const int tid = threadIdx.x;
    const int n = blockIdx.x * 256 + tid;
    const int b = n >> 12;
    const int t = n & 4095;
    const float* zb = z + ((size_t)b * DD) * TD + t;
    float* ob = zq_out + ((size_t)b * DD) * TD + t;
    const int bi = idx_ws[n];
    const float* e = newE + (size_t)bi * DD;
    double acc = 0.0;
#pragma unroll
    for (int d = 0; d < DD; ++d) {
        float q = e[d];
        float zv = zb[(size_t)d * TD];
        ob[(size_t)d * TD] = q;
        float df = zv - q;
        acc = fma((double)df, (double)df, acc);
    }
    for (int off = 32; off > 0; off >>= 1) acc += __shfl_down(acc, off, 64);
    __shared__ double wsum[4];
    const int wid = tid >> 6, lane = tid & 63;
    if (lane == 0) wsum[wid] = acc;
    __syncthreads();
    if (tid == 0) {
        atomicAdd(loss_acc, wsum[0] + wsum[1] + wsum[2] + wsum[3]);
        __threadfence();
        const int prev = atomicAdd(done_cnt, 1);
        if (prev == gridDim.x - 1) {
            __threadfence();
            *loss_out = (float)(0.25 * (*loss_acc) / (double)(N_PTS * DD));
        }
    }
}

extern "C" void kernel_launch(void* const* d_in, const int* in_sizes, int n_in,
                              void* d_out, int out_size, void* d_ws, size_t ws_size,
                              hipStream_t stream) {
    const float* z    = (const float*)d_in[0];   // [32, 64, 4096]
    const float* emb  = (const float*)d_in[1];   // [1024, 64]
    const float* cs   = (const float*)d_in[2];   // [1024]
    const float* avg  = (const float*)d_in[3];   // [1024, 64]

    float* out      = (float*)d_out;
    float* zq_out   = out;                // 8388608 floats (32 MiB)
    float* loss_out = out + 8388608;      // 1
    float* ind_out  = out + 8388609;      // 131072 (indices as float)

    // z_hi/z_lo bf16 [N][D] exactly fill the z_q region (dead before K4 rewrites it)
    unsigned short* zh = (unsigned short*)d_out;                       // 16 MiB
    unsigned short* zl = (unsigned short*)((char*)d_out + 16777216);   // 16 MiB

    char* ws = (char*)d_ws;
    int*            idx_ws   = (int*)ws;                     // 512 KB @ 0
    float*          newE     = (float*)(ws + 524288);        // 256 KB
    double*         dnn      = (double*)(ws + 524288);       // 8 KB: lives in newE region
                                                             // (dead until vq_newE, which
                                                             // runs after vq_fallback)
    float*          esum     = (float*)(ws + 786432);        // 256 KB [memset]
    int*            hist     = (int*)(ws + 1048576);         // 4 KB   [memset]
    int*            nflag    = (int*)(ws + 1052672);         // 4 B    [memset]
    int*            done_cnt = (int*)(ws + 1052676);         // 4 B    [memset]
    double*         loss_acc = (double*)(ws + 1052680);      // 8 B    [memset]
    float*          halfnorm = (float*)(ws + 1052688);       // 4 KB
    int*            cursor   = (int*)(ws + 1056784);         // 4 KB
    int*            flags    = (int*)(ws + 1060880);         // 512 KB
    int*            order    = (int*)(ws + 1585168);         // 512 KB
    unsigned short* efh      = (unsigned short*)(ws + 2109456); // 128 KB (fragment-ordered hi)
    unsigned short* efl      = (unsigned short*)(ws + 2240528); // 128 KB (fragment-ordered lo)
    float*          rsmo     = (float*)(ws + 2371600);       // 4 KB (end ~2.38 MB)

    // zero esum + hist + nflag + done_cnt + loss_acc (contiguous 786432..1052688)
    hipMemsetAsync(ws + 786432, 0, 266256, stream);

    vq_eprep<<<4, 256, 0, stream>>>(emb, efh, efl, halfnorm, dnn);
    vq_screen_mfma<<<N_PTS / 128, 256, 0, stream>>>(z, zh, zl, efh, efl, halfnorm,
                                                    idx_ws, ind_out, nflag, flags, hist);
    vq_fallback<<<1024, 256, 0, stream>>>(z, emb, dnn, idx_ws, ind_out, nflag, flags, hist);
    vq_prefix_smo<<<1, 1024, 0, stream>>>(hist, cs, cursor, rsmo);
    vq_scatter<<<N_PTS / 256, 256, 0, stream>>>(idx_ws, cursor, order);
    vq_esum2<<<N_PTS / 256, 256, 0, stream>>>(zh, zl, idx_ws, order, esum);
    vq_newE<<<256, 256, 0, stream>>>(avg, esum, rsmo, newE);
    vq_gather_loss<<<N_PTS / 256, 256, 0, stream>>>(z, newE, idx_ws, zq_out,
                                                    loss_acc, done_cnt, loss_out);
}